// Round 9
// baseline (154.649 us; speedup 1.0000x reference)
//
#include <hip/hip_runtime.h>
#include <cstdint>
#include <cstring>

#define BATCH   4096
#define DIM     128
#define NLAYERS 8
#define KNODES  8
#define NDEG    4
#define NNODES  65
#define NODE_ELEMS (BATCH * DIM)   // 524288 elems
#define ROWS    16                  // rows per block tile
#define SLOTS   37                  // LDS-resident activation slots
#define TILE_B  (ROWS * 256)        // 4096 B per bf16 tile (16 rows x 128 cols)
#define NTHREADS 1024

typedef float    f32x4 __attribute__((ext_vector_type(4)));
typedef short    s16x8 __attribute__((ext_vector_type(8)));
typedef uint32_t u32x4 __attribute__((ext_vector_type(4)));

struct LayerSrcs { int p[KNODES][NDEG]; };

struct Sched {
  uint64_t pinfo[NLAYERS * KNODES];  // per node: 4 x {slot+1 (8b), src node id (8b)}
  int8_t   dst[NLAYERS * KNODES];    // >=0 LDS slot, -1 global spill, -2 mean-only, -3 dead
  int8_t   root_dst;
  uint32_t spillmask;                // bit l: layer l writes a spilled node -> full barrier
};

// ---------------- device helpers ----------------
__device__ __forceinline__ uint32_t f2bf(float f) {   // RNE round to bf16
  union { float f; uint32_t i; } x; x.f = f;
  return (x.i + 0x7fffu + ((x.i >> 16) & 1u)) >> 16;
}
__device__ __forceinline__ uint32_t pack2(float a, float b) {
  return f2bf(a) | (f2bf(b) << 16);
}
// Barrier that drains only LDS ops (ds_write/ds_read/ds_atomic are lgkm).
// Global W prefetch loads stay in flight across it (T4: never vmcnt(0) in loop).
__device__ __forceinline__ void barrier_lgkm() {
  asm volatile("s_waitcnt lgkmcnt(0)\n\ts_barrier" ::: "memory");
}

// ---------------- W pre-pack: f32 row-major -> bf16 MFMA-fragment-linear ----------------
// chunk ci = (node*4 + ks)*8 + panel; elem offset = ci*512 + lane*8.
// element e = W[node][col = panel*16 + (lane&15)][k = ks*32 + (lane>>4)*8 + e]
__global__ __launch_bounds__(256)
void pack_w(const float* __restrict__ W, uint16_t* __restrict__ Wp) {
  int gid  = blockIdx.x * 256 + threadIdx.x;     // 65*2048 = 133120 total
  int lane = gid & 63;
  int n    = (gid >> 6) & 7;
  int ks   = (gid >> 9) & 3;
  int node = gid >> 11;
  int col  = n * 16 + (lane & 15);
  int k0   = ks * 32 + (lane >> 4) * 8;
  const float* src = W + ((size_t)node * DIM + col) * DIM + k0;
  f32x4 v0 = *(const f32x4*)src;
  f32x4 v1 = *(const f32x4*)(src + 4);
  u32x4 pk;
  pk.x = pack2(v0.x, v0.y); pk.y = pack2(v0.z, v0.w);
  pk.z = pack2(v1.x, v1.y); pk.w = pack2(v1.z, v1.w);
  *(u32x4*)(Wp + (size_t)gid * 8) = pk;
}

// ---------------- the persistent DAG executor ----------------
// 16 waves = 8 nodes x 2 col-halves, one lgkm-only barrier per layer.
// W fragments for layer l+1 are issued at the end of layer l and stay in
// flight ACROSS the barrier (read-only data; no dependence on the barrier).
__global__ __launch_bounds__(NTHREADS, 4)
void dag_exec(const float* __restrict__ X, const uint16_t* __restrict__ Wp,
              const float* __restrict__ bias, uint16_t* __restrict__ outs,
              float* __restrict__ out, Sched sch)
{
  __shared__ char lds[SLOTS * TILE_B + 2048 * 4];   // 37 slots + f32 mean buffer = 156 KB
  float* mb = (float*)(lds + (size_t)SLOTS * TILE_B);

  const int t    = threadIdx.x;
  const int lane = t & 63;
  const int wv   = t >> 6;
  const int lr   = lane & 15;
  const int lg   = lane >> 4;
  const int kn   = wv & 7;      // node within layer
  const int h    = wv >> 3;     // col half (64 cols)
  const int row0 = blockIdx.x * ROWS;

  mb[t] = 0.f;
  mb[t + 1024] = 0.f;

  s16x8 wf[2][4][4];   // double-buffered W fragments; all indices compile-time

#define PREFETCH_WF(buf, node_) do {                                          \
    const uint16_t* wb_ = Wp + ((((size_t)(node_) * 4) * 8 + h * 4) << 9)     \
                          + lane * 8;                                         \
    _Pragma("unroll") for (int ks_ = 0; ks_ < 4; ++ks_)                       \
    _Pragma("unroll") for (int n_ = 0; n_ < 4; ++n_)                          \
      wf[buf][ks_][n_] = *(const s16x8*)(wb_ + (size_t)(ks_ * 8 + n_) * 512); \
  } while (0)

  // ---- root: node 0, A = bf16(X); 8 waves, one col-panel each ----
  if (wv < 8) {
    f32x4 acc = (f32x4){0.f, 0.f, 0.f, 0.f};
    s16x8 rwf[4];
#pragma unroll
    for (int ks = 0; ks < 4; ++ks)
      rwf[ks] = *(const s16x8*)(Wp + (((size_t)ks * 8 + wv) << 9) + lane * 8);
#pragma unroll
    for (int ks = 0; ks < 4; ++ks) {
      const float* xp = X + (size_t)(row0 + lr) * DIM + ks * 32 + lg * 8;
      f32x4 v0 = *(const f32x4*)xp;
      f32x4 v1 = *(const f32x4*)(xp + 4);
      u32x4 pk;
      pk.x = pack2(v0.x, v0.y); pk.y = pack2(v0.z, v0.w);
      pk.z = pack2(v1.x, v1.y); pk.w = pack2(v1.z, v1.w);
      s16x8 af;
      __builtin_memcpy(&af, &pk, 16);
      acc = __builtin_amdgcn_mfma_f32_16x16x32_bf16(af, rwf[ks], acc, 0, 0, 0);
    }
    char* db = lds + (size_t)sch.root_dst * TILE_B;
    const int col = wv * 16 + lr;
    const float bv = bias[col];
#pragma unroll
    for (int j = 0; j < 4; ++j) {
      const int row = lg * 4 + j;
      float v = fmaxf(acc[j] + bv, 0.f);
      *(uint16_t*)(db + ((row * 256 + col * 2) ^ ((row & 7) << 4))) = (uint16_t)f2bf(v);
    }
  }
  // issue layer-0 W loads for ALL waves; they stay in flight across the barrier
  PREFETCH_WF(0, 1 + kn);
  barrier_lgkm();   // root wrote LDS only (never spills): lgkm drain suffices

  // ---- 8 layers, fully unrolled so wf[l&1] indices are static ----
#pragma unroll
  for (int l = 0; l < NLAYERS; ++l) {
    const int cur  = l & 1;
    const int idx  = l * KNODES + kn;
    const int node = 1 + idx;
    const int dv   = sch.dst[idx];
    const uint64_t pinfo = sch.pinfo[idx];

    if (dv != -3) {
      // per-parent resolved bases (wave-uniform decode, per-lane address)
      const char* pbase[NDEG];
      bool pglob[NDEG];
#pragma unroll
      for (int p = 0; p < NDEG; ++p) {
        const int e  = (int)((pinfo >> (p * 16)) & 0xffff);
        const int ps = (e & 0xff) - 1;
        if (ps >= 0) {
          pbase[p] = lds + (size_t)ps * TILE_B;
          pglob[p] = false;
        } else {
          const int pid = e >> 8;
          pbase[p] = (const char*)(outs + (size_t)pid * NODE_ELEMS +
                                   (size_t)(row0 + lr) * DIM + lg * 8);
          pglob[p] = true;
        }
      }
      float bv[4];
#pragma unroll
      for (int n = 0; n < 4; ++n)
        bv[n] = bias[(size_t)node * DIM + (h * 4 + n) * 16 + lr];

      f32x4 acc[4];
#pragma unroll
      for (int n = 0; n < 4; ++n) acc[n] = (f32x4){0.f, 0.f, 0.f, 0.f};

      // MFMA cluster: af rolling depth-1, wf[cur] was loaded last layer
      s16x8 afA[NDEG], afB[NDEG];
#pragma unroll
      for (int p = 0; p < NDEG; ++p)
        afA[p] = pglob[p]
          ? *(const s16x8*)(pbase[p] + 0 * 64)
          : *(const s16x8*)(pbase[p] + ((lr * 256 + 0 * 64 + lg * 16) ^ ((lr & 7) << 4)));

      __builtin_amdgcn_s_setprio(1);
#pragma unroll
      for (int ks = 0; ks < 4; ++ks) {
        if (ks + 1 < 4) {
#pragma unroll
          for (int p = 0; p < NDEG; ++p) {
            s16x8 v = pglob[p]
              ? *(const s16x8*)(pbase[p] + (ks + 1) * 64)
              : *(const s16x8*)(pbase[p] +
                  ((lr * 256 + (ks + 1) * 64 + lg * 16) ^ ((lr & 7) << 4)));
            if (ks & 1) afA[p] = v; else afB[p] = v;
          }
        }
#pragma unroll
        for (int n = 0; n < 4; ++n)
#pragma unroll
          for (int p = 0; p < NDEG; ++p)
            acc[n] = __builtin_amdgcn_mfma_f32_16x16x32_bf16(
                (ks & 1) ? afB[p] : afA[p], wf[cur][ks][n], acc[n], 0, 0, 0);
      }
      __builtin_amdgcn_s_setprio(0);

      // W prefetch for the NEXT layer: wf[cur] registers are dead now,
      // loads overlap the epilogue + barrier + next layer's af reads.
      if (l + 1 < NLAYERS) PREFETCH_WF(cur ^ 1, 1 + (l + 1) * KNODES + kn);

      // epilogue
#pragma unroll
      for (int n = 0; n < 4; ++n) {
        const int col = (h * 4 + n) * 16 + lr;
        if (dv >= 0) {
          char* db = lds + (size_t)dv * TILE_B;
#pragma unroll
          for (int j = 0; j < 4; ++j) {
            const int row = lg * 4 + j;
            float v = fmaxf(acc[n][j] + bv[n], 0.f);
            *(uint16_t*)(db + ((row * 256 + col * 2) ^ ((row & 7) << 4))) = (uint16_t)f2bf(v);
          }
        } else if (dv == -1) {
          uint16_t* gb = outs + (size_t)node * NODE_ELEMS + (size_t)row0 * DIM + col;
#pragma unroll
          for (int j = 0; j < 4; ++j) {
            const int row = lg * 4 + j;
            float v = fmaxf(acc[n][j] + bv[n], 0.f);
            gb[(size_t)row * DIM] = (uint16_t)f2bf(v);
          }
        } else {  // -2: accumulate into f32 mean buffer
#pragma unroll
          for (int j = 0; j < 4; ++j) {
            const int row = lg * 4 + j;
            float v = fmaxf(acc[n][j] + bv[n], 0.f);
            atomicAdd(mb + row * DIM + col, v);
          }
        }
      }
    } else {
      // dead node: still keep the pipeline shape (prefetch next layer's W)
      if (l + 1 < NLAYERS) PREFETCH_WF(cur ^ 1, 1 + (l + 1) * KNODES + kn);
    }

    // layer barrier: lgkm-only unless this layer wrote a spilled node to global
    if (sch.spillmask & (1u << l)) __syncthreads();
    else                           barrier_lgkm();
  }

  // ---- mean store (f32), coalesced ----
  {
    const int r = t >> 7, c = t & 127;
    out[(size_t)(row0 + r) * DIM + c]     = mb[t] * 0.125f;
    out[(size_t)(row0 + 8 + r) * DIM + c] = mb[t + 1024] * 0.125f;
  }
#undef PREFETCH_WF
}

// ---------------- host: replicate np.random.default_rng(0) graph ----------------
namespace nprng {
static inline uint32_t hashmix(uint32_t v, uint32_t& hc) {
  v ^= hc; hc *= 0x931e8875u; v *= hc; v ^= v >> 16; return v;
}
static inline uint32_t mixf(uint32_t x, uint32_t y) {
  uint32_t r = x * 0xca01f9ddu - y * 0x4973f715u;
  r ^= r >> 16;
  return r;
}
struct Pcg {
  unsigned __int128 state, inc;
  bool has32; uint32_t saved;
  void step() {
    const unsigned __int128 MUL =
        ((unsigned __int128)2549297995355413924ULL << 64) | 4865540595714422341ULL;
    state = state * MUL + inc;
  }
  void init_seed0() {
    uint32_t pool[4];
    uint32_t hc = 0x43b0d7e5u;
    for (int i = 0; i < 4; ++i) pool[i] = hashmix(0u, hc);
    for (int s = 0; s < 4; ++s)
      for (int d = 0; d < 4; ++d)
        if (s != d) pool[d] = mixf(pool[d], hashmix(pool[s], hc));
    uint32_t st[8];
    uint32_t hb = 0x8b51f9ddu;
    int cyc = 0;
    for (int i = 0; i < 8; ++i) {
      uint32_t dv = pool[cyc]; cyc = (cyc + 1) & 3;
      dv ^= hb; hb *= 0x58f38dedu; dv *= hb; dv ^= dv >> 16;
      st[i] = dv;
    }
    uint64_t v[4];
    for (int i = 0; i < 4; ++i)
      v[i] = (uint64_t)st[2 * i] | ((uint64_t)st[2 * i + 1] << 32);
    unsigned __int128 s128 = ((unsigned __int128)v[0] << 64) | v[1];
    unsigned __int128 i128 = ((unsigned __int128)v[2] << 64) | v[3];
    state = 0; inc = (i128 << 1) | 1;
    step(); state += s128; step();
    has32 = false; saved = 0;
  }
  uint64_t next64() {
    step();
    uint64_t rot = (uint64_t)(state >> 122);
    uint64_t x = (uint64_t)(state >> 64) ^ (uint64_t)state;
    return rot ? ((x >> rot) | (x << (64 - rot))) : x;
  }
  uint32_t next32() {
    if (has32) { has32 = false; return saved; }
    uint64_t v = next64();
    has32 = true; saved = (uint32_t)(v >> 32);
    return (uint32_t)v;
  }
  uint32_t lemire32(uint32_t rng_incl) {
    uint32_t rng_excl = rng_incl + 1u;
    uint64_t m = (uint64_t)next32() * (uint64_t)rng_excl;
    uint32_t leftover = (uint32_t)m;
    if (leftover < rng_excl) {
      uint32_t threshold = (0xFFFFFFFFu - rng_incl) % rng_excl;
      while (leftover < threshold) {
        m = (uint64_t)next32() * (uint64_t)rng_excl;
        leftover = (uint32_t)m;
      }
    }
    return (uint32_t)(m >> 32);
  }
};
}  // namespace nprng

extern "C" void kernel_launch(void* const* d_in, const int* in_sizes, int n_in,
                              void* d_out, int out_size, void* d_ws, size_t ws_size,
                              hipStream_t stream) {
  const float* X    = (const float*)d_in[0];
  const float* W    = (const float*)d_in[1];
  const float* bias = (const float*)d_in[2];
  float* out        = (float*)d_out;

  uint16_t* Wp   = (uint16_t*)d_ws;                                  // 2.13 MB packed W
  uint16_t* outs = (uint16_t*)((char*)d_ws + (size_t)NNODES * DIM * DIM * 2);  // spill space

  // ---- rebuild deterministic graph ----
  nprng::Pcg rng; rng.init_seed0();
  LayerSrcs srcs[NLAYERS];
  int n_prev = 1;
  for (int l = 0; l < NLAYERS; ++l) {
    for (int k = 0; k < KNODES; ++k)
      for (int j = 0; j < NDEG; ++j)
        srcs[l].p[k][j] = (n_prev == 1) ? 0 : (int)rng.lemire32((uint32_t)(n_prev - 1));
    n_prev += KNODES;
  }

  // ---- liveness: alive = contributes to the final mean ----
  bool alive[NNODES];
  for (int i = 0; i < NNODES; ++i) alive[i] = false;
  for (int i = NNODES - KNODES; i < NNODES; ++i) alive[i] = true;
  for (int l = NLAYERS - 1; l >= 0; --l)
    for (int k = 0; k < KNODES; ++k)
      if (alive[1 + l * KNODES + k])
        for (int j = 0; j < NDEG; ++j) alive[srcs[l].p[k][j]] = true;

  int last_use[NNODES];
  for (int i = 0; i < NNODES; ++i) last_use[i] = -1;
  for (int l = 0; l < NLAYERS; ++l)
    for (int k = 0; k < KNODES; ++k)
      if (alive[1 + l * KNODES + k])
        for (int j = 0; j < NDEG; ++j) {
          int s = srcs[l].p[k][j];
          if (l > last_use[s]) last_use[s] = l;
        }

  // ---- slot allocation (greedy, exact graph) ----
  int slot_of[NNODES];
  for (int i = 0; i < NNODES; ++i) slot_of[i] = -1;
  int freeStk[SLOTS], nfree = 0;
  for (int i = SLOTS - 1; i >= 0; --i) freeStk[nfree++] = i;

  Sched sch;
  sch.spillmask = 0;
  slot_of[0] = freeStk[--nfree];           // node 0 always alive & first
  sch.root_dst = (int8_t)slot_of[0];

  for (int l = 0; l < NLAYERS; ++l) {
    for (int k = 0; k < KNODES; ++k) {
      const int node = 1 + l * KNODES + k;
      int dv;
      if (!alive[node])            dv = -3;
      else if (l == NLAYERS - 1)   dv = -2;                 // mean-only, LDS f32 accum
      else if (nfree > 0)          dv = slot_of[node] = freeStk[--nfree];
      else                         { dv = -1; sch.spillmask |= (1u << l); }
      sch.dst[l * KNODES + k] = (int8_t)dv;

      uint64_t w64 = 0;
      for (int j = 0; j < NDEG; ++j) {
        const int src = srcs[l].p[k][j];
        const int enc = ((slot_of[src] + 1) & 0xff) | (src << 8);
        w64 |= (uint64_t)enc << (j * 16);
      }
      sch.pinfo[l * KNODES + k] = w64;
    }
    // free slots whose last use was this layer (reusable from layer l+1 on)
    for (int n = 0; n < NNODES; ++n)
      if (slot_of[n] >= 0 && last_use[n] == l) {
        freeStk[nfree++] = slot_of[n];
        slot_of[n] = -1;
      }
  }

  // ---- launch: 2 kernels total ----
  pack_w<<<dim3(520), dim3(256), 0, stream>>>(W, Wp);
  dag_exec<<<dim3(BATCH / ROWS), dim3(NTHREADS), 0, stream>>>(X, Wp, bias, outs, out, sch);
}

// Round 10
// 121.195 us; speedup vs baseline: 1.2760x; 1.2760x over previous
//
#include <hip/hip_runtime.h>
#include <cstdint>
#include <cstring>

#define BATCH   4096
#define DIM     128
#define NLAYERS 8
#define KNODES  8
#define NDEG    4
#define NNODES  65
#define NODE_ELEMS (BATCH * DIM)   // 524288 elems
#define ROWS    16                  // rows per block tile
#define SLOTS   37                  // LDS-resident activation slots
#define TILE_B  (ROWS * 256)        // 4096 B per bf16 tile (16 rows x 128 cols)
#define NTHREADS 1024

typedef float    f32x4 __attribute__((ext_vector_type(4)));
typedef short    s16x8 __attribute__((ext_vector_type(8)));
typedef uint32_t u32x4 __attribute__((ext_vector_type(4)));

struct LayerSrcs { int p[KNODES][NDEG]; };

struct Sched {
  uint64_t pinfo[NLAYERS * KNODES];  // per node: 4 x {slot+1 (8b), src node id (8b)}
  int8_t   dst[NLAYERS * KNODES];    // >=0 LDS slot, -1 global spill, -2 mean-only, -3 dead
  int8_t   root_dst;
};

// ---------------- device helpers ----------------
__device__ __forceinline__ uint32_t f2bf(float f) {   // RNE round to bf16
  union { float f; uint32_t i; } x; x.f = f;
  return (x.i + 0x7fffu + ((x.i >> 16) & 1u)) >> 16;
}
__device__ __forceinline__ uint32_t pack2(float a, float b) {
  return f2bf(a) | (f2bf(b) << 16);
}

// ---------------- W pre-pack: f32 row-major -> bf16 MFMA-fragment-linear ----------------
// chunk ci = (node*4 + ks)*8 + panel; elem offset = ci*512 + lane*8.
// element e = W[node][col = panel*16 + (lane&15)][k = ks*32 + (lane>>4)*8 + e]
__global__ __launch_bounds__(256)
void pack_w(const float* __restrict__ W, uint16_t* __restrict__ Wp) {
  int gid  = blockIdx.x * 256 + threadIdx.x;     // 65*2048 = 133120 total
  int lane = gid & 63;
  int n    = (gid >> 6) & 7;
  int ks   = (gid >> 9) & 3;
  int node = gid >> 11;
  int col  = n * 16 + (lane & 15);
  int k0   = ks * 32 + (lane >> 4) * 8;
  const float* src = W + ((size_t)node * DIM + col) * DIM + k0;
  f32x4 v0 = *(const f32x4*)src;
  f32x4 v1 = *(const f32x4*)(src + 4);
  u32x4 pk;
  pk.x = pack2(v0.x, v0.y); pk.y = pack2(v0.z, v0.w);
  pk.z = pack2(v1.x, v1.y); pk.w = pack2(v1.z, v1.w);
  *(u32x4*)(Wp + (size_t)gid * 8) = pk;
}

// ---------------- the persistent DAG executor ----------------
// 1024 threads = 16 waves = 8 nodes x 2 col-halves. One barrier per layer.
// Parent sum folded into the MFMA accumulator (K=512 over 4 parents).
// R10 change vs the best-known R4 kernel: BLOCK-ROTATED NODE ASSIGNMENT.
// kn = ((wv&7)+blockIdx)&7 decorrelates the cross-block W streams so the 32
// blocks per XCD don't all read the same L2 lines in barrier lockstep
// (L2-broadcast-contention theory; numerics bit-identical, pure remap).
__global__ __launch_bounds__(NTHREADS)
void dag_exec(const float* __restrict__ X, const uint16_t* __restrict__ Wp,
              const float* __restrict__ bias, uint16_t* __restrict__ outs,
              float* __restrict__ out, Sched sch)
{
  __shared__ char lds[SLOTS * TILE_B + 2048 * 4];   // 37 slots + f32 mean buffer = 156 KB
  float* mb = (float*)(lds + (size_t)SLOTS * TILE_B);

  const int t    = threadIdx.x;
  const int lane = t & 63;
  const int wv   = t >> 6;
  const int lr   = lane & 15;
  const int lg   = lane >> 4;
  const int kn   = ((wv & 7) + blockIdx.x) & 7;   // block-rotated node within layer
  const int h    = wv >> 3;     // col half (64 cols)
  const int row0 = blockIdx.x * ROWS;

  mb[t] = 0.f;
  mb[t + 1024] = 0.f;

  // ---- root: node 0, A = bf16(X) read straight from global; 2 waves active ----
  if (wv < 2) {
    const int h2 = wv;
    f32x4 acc[4];
#pragma unroll
    for (int n = 0; n < 4; ++n) acc[n] = (f32x4){0.f, 0.f, 0.f, 0.f};
#pragma unroll
    for (int ks = 0; ks < 4; ++ks) {
      const float* xp = X + (size_t)(row0 + lr) * DIM + ks * 32 + lg * 8;
      f32x4 v0 = *(const f32x4*)xp;
      f32x4 v1 = *(const f32x4*)(xp + 4);
      u32x4 pk;
      pk.x = pack2(v0.x, v0.y); pk.y = pack2(v0.z, v0.w);
      pk.z = pack2(v1.x, v1.y); pk.w = pack2(v1.z, v1.w);
      s16x8 af;
      __builtin_memcpy(&af, &pk, 16);
#pragma unroll
      for (int n = 0; n < 4; ++n) {
        const size_t ci = ((size_t)(0 * 4 + ks) * 8 + h2 * 4 + n);
        s16x8 wf = *(const s16x8*)(Wp + (ci << 9) + lane * 8);
        acc[n] = __builtin_amdgcn_mfma_f32_16x16x32_bf16(af, wf, acc[n], 0, 0, 0);
      }
    }
    char* db = lds + (size_t)sch.root_dst * TILE_B;
#pragma unroll
    for (int n = 0; n < 4; ++n) {
      const int col = (h2 * 4 + n) * 16 + lr;
      const float bv = bias[col];
#pragma unroll
      for (int j = 0; j < 4; ++j) {
        const int row = lg * 4 + j;
        float v = fmaxf(acc[n][j] + bv, 0.f);
        *(uint16_t*)(db + ((row * 256 + col * 2) ^ ((row & 7) << 4))) = (uint16_t)f2bf(v);
      }
    }
  }
  __syncthreads();

  // ---- 8 layers, one wave-task per (node, col-half), one barrier per layer ----
  for (int l = 0; l < NLAYERS; ++l) {
    const int idx  = l * KNODES + kn;
    const int node = 1 + idx;
    const int dv   = sch.dst[idx];
    const uint64_t pinfo = sch.pinfo[idx];

    if (dv != -3) {
      f32x4 acc[4];
#pragma unroll
      for (int n = 0; n < 4; ++n) acc[n] = (f32x4){0.f, 0.f, 0.f, 0.f};

#pragma unroll
      for (int ks = 0; ks < 4; ++ks) {
        s16x8 af[NDEG];
#pragma unroll
        for (int p = 0; p < NDEG; ++p) {
          const int e  = (int)((pinfo >> (p * 16)) & 0xffff);
          const int ps = (e & 0xff) - 1;
          if (ps >= 0) {
            af[p] = *(const s16x8*)(lds + (size_t)ps * TILE_B +
                     ((lr * 256 + ks * 64 + lg * 16) ^ ((lr & 7) << 4)));
          } else {
            const int pid = e >> 8;
            af[p] = *(const s16x8*)(outs + (size_t)pid * NODE_ELEMS +
                     (size_t)(row0 + lr) * DIM + ks * 32 + lg * 8);
          }
        }
#pragma unroll
        for (int n = 0; n < 4; ++n) {
          const size_t ci = ((size_t)node * 4 + ks) * 8 + h * 4 + n;
          s16x8 wf = *(const s16x8*)(Wp + (ci << 9) + lane * 8);
#pragma unroll
          for (int p = 0; p < NDEG; ++p)
            acc[n] = __builtin_amdgcn_mfma_f32_16x16x32_bf16(af[p], wf, acc[n], 0, 0, 0);
        }
      }

      // epilogue
#pragma unroll
      for (int n = 0; n < 4; ++n) {
        const int col = (h * 4 + n) * 16 + lr;
        const float bv = bias[(size_t)node * DIM + col];
        if (dv >= 0) {
          char* db = lds + (size_t)dv * TILE_B;
#pragma unroll
          for (int j = 0; j < 4; ++j) {
            const int row = lg * 4 + j;
            float v = fmaxf(acc[n][j] + bv, 0.f);
            *(uint16_t*)(db + ((row * 256 + col * 2) ^ ((row & 7) << 4))) = (uint16_t)f2bf(v);
          }
        } else if (dv == -1) {
          uint16_t* gb = outs + (size_t)node * NODE_ELEMS + (size_t)row0 * DIM + col;
#pragma unroll
          for (int j = 0; j < 4; ++j) {
            const int row = lg * 4 + j;
            float v = fmaxf(acc[n][j] + bv, 0.f);
            gb[(size_t)row * DIM] = (uint16_t)f2bf(v);
          }
        } else {  // -2: accumulate into f32 mean buffer
#pragma unroll
          for (int j = 0; j < 4; ++j) {
            const int row = lg * 4 + j;
            float v = fmaxf(acc[n][j] + bv, 0.f);
            atomicAdd(mb + row * DIM + col, v);
          }
        }
      }
    }
    __syncthreads();
  }

  // ---- mean store (f32), coalesced ----
  {
    const int r = t >> 7, c = t & 127;
    out[(size_t)(row0 + r) * DIM + c]     = mb[t] * 0.125f;
    out[(size_t)(row0 + 8 + r) * DIM + c] = mb[t + 1024] * 0.125f;
  }
}

// ---------------- host: replicate np.random.default_rng(0) graph ----------------
namespace nprng {
static inline uint32_t hashmix(uint32_t v, uint32_t& hc) {
  v ^= hc; hc *= 0x931e8875u; v *= hc; v ^= v >> 16; return v;
}
static inline uint32_t mixf(uint32_t x, uint32_t y) {
  uint32_t r = x * 0xca01f9ddu - y * 0x4973f715u;
  r ^= r >> 16;
  return r;
}
struct Pcg {
  unsigned __int128 state, inc;
  bool has32; uint32_t saved;
  void step() {
    const unsigned __int128 MUL =
        ((unsigned __int128)2549297995355413924ULL << 64) | 4865540595714422341ULL;
    state = state * MUL + inc;
  }
  void init_seed0() {
    uint32_t pool[4];
    uint32_t hc = 0x43b0d7e5u;
    for (int i = 0; i < 4; ++i) pool[i] = hashmix(0u, hc);
    for (int s = 0; s < 4; ++s)
      for (int d = 0; d < 4; ++d)
        if (s != d) pool[d] = mixf(pool[d], hashmix(pool[s], hc));
    uint32_t st[8];
    uint32_t hb = 0x8b51f9ddu;
    int cyc = 0;
    for (int i = 0; i < 8; ++i) {
      uint32_t dv = pool[cyc]; cyc = (cyc + 1) & 3;
      dv ^= hb; hb *= 0x58f38dedu; dv *= hb; dv ^= dv >> 16;
      st[i] = dv;
    }
    uint64_t v[4];
    for (int i = 0; i < 4; ++i)
      v[i] = (uint64_t)st[2 * i] | ((uint64_t)st[2 * i + 1] << 32);
    unsigned __int128 s128 = ((unsigned __int128)v[0] << 64) | v[1];
    unsigned __int128 i128 = ((unsigned __int128)v[2] << 64) | v[3];
    state = 0; inc = (i128 << 1) | 1;
    step(); state += s128; step();
    has32 = false; saved = 0;
  }
  uint64_t next64() {
    step();
    uint64_t rot = (uint64_t)(state >> 122);
    uint64_t x = (uint64_t)(state >> 64) ^ (uint64_t)state;
    return rot ? ((x >> rot) | (x << (64 - rot))) : x;
  }
  uint32_t next32() {
    if (has32) { has32 = false; return saved; }
    uint64_t v = next64();
    has32 = true; saved = (uint32_t)(v >> 32);
    return (uint32_t)v;
  }
  uint32_t lemire32(uint32_t rng_incl) {
    uint32_t rng_excl = rng_incl + 1u;
    uint64_t m = (uint64_t)next32() * (uint64_t)rng_excl;
    uint32_t leftover = (uint32_t)m;
    if (leftover < rng_excl) {
      uint32_t threshold = (0xFFFFFFFFu - rng_incl) % rng_excl;
      while (leftover < threshold) {
        m = (uint64_t)next32() * (uint64_t)rng_excl;
        leftover = (uint32_t)m;
      }
    }
    return (uint32_t)(m >> 32);
  }
};
}  // namespace nprng

extern "C" void kernel_launch(void* const* d_in, const int* in_sizes, int n_in,
                              void* d_out, int out_size, void* d_ws, size_t ws_size,
                              hipStream_t stream) {
  const float* X    = (const float*)d_in[0];
  const float* W    = (const float*)d_in[1];
  const float* bias = (const float*)d_in[2];
  float* out        = (float*)d_out;

  uint16_t* Wp   = (uint16_t*)d_ws;                                  // 2.13 MB packed W
  uint16_t* outs = (uint16_t*)((char*)d_ws + (size_t)NNODES * DIM * DIM * 2);  // spill space

  // ---- rebuild deterministic graph ----
  nprng::Pcg rng; rng.init_seed0();
  LayerSrcs srcs[NLAYERS];
  int n_prev = 1;
  for (int l = 0; l < NLAYERS; ++l) {
    for (int k = 0; k < KNODES; ++k)
      for (int j = 0; j < NDEG; ++j)
        srcs[l].p[k][j] = (n_prev == 1) ? 0 : (int)rng.lemire32((uint32_t)(n_prev - 1));
    n_prev += KNODES;
  }

  // ---- liveness: alive = contributes to the final mean ----
  bool alive[NNODES];
  for (int i = 0; i < NNODES; ++i) alive[i] = false;
  for (int i = NNODES - KNODES; i < NNODES; ++i) alive[i] = true;
  for (int l = NLAYERS - 1; l >= 0; --l)
    for (int k = 0; k < KNODES; ++k)
      if (alive[1 + l * KNODES + k])
        for (int j = 0; j < NDEG; ++j) alive[srcs[l].p[k][j]] = true;

  int last_use[NNODES];
  for (int i = 0; i < NNODES; ++i) last_use[i] = -1;
  for (int l = 0; l < NLAYERS; ++l)
    for (int k = 0; k < KNODES; ++k)
      if (alive[1 + l * KNODES + k])
        for (int j = 0; j < NDEG; ++j) {
          int s = srcs[l].p[k][j];
          if (l > last_use[s]) last_use[s] = l;
        }

  // ---- slot allocation (greedy, exact graph) ----
  int slot_of[NNODES];
  for (int i = 0; i < NNODES; ++i) slot_of[i] = -1;
  int freeStk[SLOTS], nfree = 0;
  for (int i = SLOTS - 1; i >= 0; --i) freeStk[nfree++] = i;

  Sched sch;
  slot_of[0] = freeStk[--nfree];           // node 0 always alive & first
  sch.root_dst = (int8_t)slot_of[0];

  for (int l = 0; l < NLAYERS; ++l) {
    for (int k = 0; k < KNODES; ++k) {
      const int node = 1 + l * KNODES + k;
      int dv;
      if (!alive[node])            dv = -3;
      else if (l == NLAYERS - 1)   dv = -2;                 // mean-only, LDS f32 accum
      else if (nfree > 0)          dv = slot_of[node] = freeStk[--nfree];
      else                         dv = -1;                 // global spill
      sch.dst[l * KNODES + k] = (int8_t)dv;

      uint64_t w64 = 0;
      for (int j = 0; j < NDEG; ++j) {
        const int src = srcs[l].p[k][j];
        const int enc = ((slot_of[src] + 1) & 0xff) | (src << 8);
        w64 |= (uint64_t)enc << (j * 16);
      }
      sch.pinfo[l * KNODES + k] = w64;
    }
    // free slots whose last use was this layer (reusable from layer l+1 on)
    for (int n = 0; n < NNODES; ++n)
      if (slot_of[n] >= 0 && last_use[n] == l) {
        freeStk[nfree++] = slot_of[n];
        slot_of[n] = -1;
      }
  }

  // ---- launch: 2 kernels total ----
  pack_w<<<dim3(520), dim3(256), 0, stream>>>(W, Wp);
  dag_exec<<<dim3(BATCH / ROWS), dim3(NTHREADS), 0, stream>>>(X, Wp, bias, outs, out, sch);
}

// Round 11
// 119.273 us; speedup vs baseline: 1.2966x; 1.0161x over previous
//
#include <hip/hip_runtime.h>
#include <cstdint>
#include <cstring>

#define BATCH   4096
#define DIM     128
#define NLAYERS 8
#define KNODES  8
#define NDEG    4
#define NNODES  65
#define NODE_ELEMS (BATCH * DIM)   // 524288 elems
#define ROWS    16                  // rows per block tile
#define SLOTS   37                  // LDS-resident activation slots
#define TILE_B  (ROWS * 256)        // 4096 B per bf16 tile (16 rows x 128 cols)
#define NTHREADS 1024

typedef float    f32x4 __attribute__((ext_vector_type(4)));
typedef short    s16x8 __attribute__((ext_vector_type(8)));
typedef uint32_t u32x4 __attribute__((ext_vector_type(4)));

struct LayerSrcs { int p[KNODES][NDEG]; };

struct Sched {
  uint64_t pinfo[NLAYERS * KNODES];  // per node: 4 x {slot+1 (8b), src node id (8b)}
  int8_t   dst[NLAYERS * KNODES];    // >=0 LDS slot, -1 global spill, -2 mean-only, -3 dead
  int8_t   root_dst;
};

// ---------------- device helpers ----------------
__device__ __forceinline__ uint32_t f2bf(float f) {   // RNE round to bf16
  union { float f; uint32_t i; } x; x.f = f;
  return (x.i + 0x7fffu + ((x.i >> 16) & 1u)) >> 16;
}
__device__ __forceinline__ uint32_t pack2(float a, float b) {
  return f2bf(a) | (f2bf(b) << 16);
}

// ---------------- W pre-pack: f32 row-major -> bf16 MFMA-fragment-linear ----------------
// chunk ci = (node*4 + ks)*8 + panel; elem offset = ci*512 + lane*8.
// element e = W[node][col = panel*16 + (lane&15)][k = ks*32 + (lane>>4)*8 + e]
__global__ __launch_bounds__(256)
void pack_w(const float* __restrict__ W, uint16_t* __restrict__ Wp) {
  int gid  = blockIdx.x * 256 + threadIdx.x;     // 65*2048 = 133120 total
  int lane = gid & 63;
  int n    = (gid >> 6) & 7;
  int ks   = (gid >> 9) & 3;
  int node = gid >> 11;
  int col  = n * 16 + (lane & 15);
  int k0   = ks * 32 + (lane >> 4) * 8;
  const float* src = W + ((size_t)node * DIM + col) * DIM + k0;
  f32x4 v0 = *(const f32x4*)src;
  f32x4 v1 = *(const f32x4*)(src + 4);
  u32x4 pk;
  pk.x = pack2(v0.x, v0.y); pk.y = pack2(v0.z, v0.w);
  pk.z = pack2(v1.x, v1.y); pk.w = pack2(v1.z, v1.w);
  *(u32x4*)(Wp + (size_t)gid * 8) = pk;
}

// ---------------- the persistent DAG executor ----------------
// 1024 threads = 16 waves = 8 nodes x 2 col-halves. One barrier per layer.
// Parent sum folded into the MFMA accumulator (K=512 over 4 parents).
// R11: WITHIN-XCD block-rotated node assignment. Blocks land on XCDs
// round-robin (same-XCD blocks have blockIdx = xcd (mod 8)), so the rotation
// must use blockIdx>>3 (R10's blockIdx&7-based rotation was constant per XCD
// -> invalid A/B). Now the 32 blocks of an XCD spread over all 8 nodes' W
// regions at any instant instead of hammering one. Bit-identical numerics.
__global__ __launch_bounds__(NTHREADS)
void dag_exec(const float* __restrict__ X, const uint16_t* __restrict__ Wp,
              const float* __restrict__ bias, uint16_t* __restrict__ outs,
              float* __restrict__ out, Sched sch)
{
  __shared__ char lds[SLOTS * TILE_B + 2048 * 4];   // 37 slots + f32 mean buffer = 156 KB
  float* mb = (float*)(lds + (size_t)SLOTS * TILE_B);

  const int t    = threadIdx.x;
  const int lane = t & 63;
  const int wv   = t >> 6;
  const int lr   = lane & 15;
  const int lg   = lane >> 4;
  const int kn   = ((wv & 7) + (blockIdx.x >> 3)) & 7;  // within-XCD rotation
  const int h    = wv >> 3;     // col half (64 cols)
  const int row0 = blockIdx.x * ROWS;

  mb[t] = 0.f;
  mb[t + 1024] = 0.f;

  // ---- root: node 0, A = bf16(X) read straight from global; 2 waves active ----
  if (wv < 2) {
    const int h2 = wv;
    f32x4 acc[4];
#pragma unroll
    for (int n = 0; n < 4; ++n) acc[n] = (f32x4){0.f, 0.f, 0.f, 0.f};
#pragma unroll
    for (int ks = 0; ks < 4; ++ks) {
      const float* xp = X + (size_t)(row0 + lr) * DIM + ks * 32 + lg * 8;
      f32x4 v0 = *(const f32x4*)xp;
      f32x4 v1 = *(const f32x4*)(xp + 4);
      u32x4 pk;
      pk.x = pack2(v0.x, v0.y); pk.y = pack2(v0.z, v0.w);
      pk.z = pack2(v1.x, v1.y); pk.w = pack2(v1.z, v1.w);
      s16x8 af;
      __builtin_memcpy(&af, &pk, 16);
#pragma unroll
      for (int n = 0; n < 4; ++n) {
        const size_t ci = ((size_t)(0 * 4 + ks) * 8 + h2 * 4 + n);
        s16x8 wf = *(const s16x8*)(Wp + (ci << 9) + lane * 8);
        acc[n] = __builtin_amdgcn_mfma_f32_16x16x32_bf16(af, wf, acc[n], 0, 0, 0);
      }
    }
    char* db = lds + (size_t)sch.root_dst * TILE_B;
#pragma unroll
    for (int n = 0; n < 4; ++n) {
      const int col = (h2 * 4 + n) * 16 + lr;
      const float bv = bias[col];
#pragma unroll
      for (int j = 0; j < 4; ++j) {
        const int row = lg * 4 + j;
        float v = fmaxf(acc[n][j] + bv, 0.f);
        *(uint16_t*)(db + ((row * 256 + col * 2) ^ ((row & 7) << 4))) = (uint16_t)f2bf(v);
      }
    }
  }
  __syncthreads();

  // ---- 8 layers, one wave-task per (node, col-half), one barrier per layer ----
  for (int l = 0; l < NLAYERS; ++l) {
    const int idx  = l * KNODES + kn;
    const int node = 1 + idx;
    const int dv   = sch.dst[idx];
    const uint64_t pinfo = sch.pinfo[idx];

    if (dv != -3) {
      f32x4 acc[4];
#pragma unroll
      for (int n = 0; n < 4; ++n) acc[n] = (f32x4){0.f, 0.f, 0.f, 0.f};

#pragma unroll
      for (int ks = 0; ks < 4; ++ks) {
        s16x8 af[NDEG];
#pragma unroll
        for (int p = 0; p < NDEG; ++p) {
          const int e  = (int)((pinfo >> (p * 16)) & 0xffff);
          const int ps = (e & 0xff) - 1;
          if (ps >= 0) {
            af[p] = *(const s16x8*)(lds + (size_t)ps * TILE_B +
                     ((lr * 256 + ks * 64 + lg * 16) ^ ((lr & 7) << 4)));
          } else {
            const int pid = e >> 8;
            af[p] = *(const s16x8*)(outs + (size_t)pid * NODE_ELEMS +
                     (size_t)(row0 + lr) * DIM + ks * 32 + lg * 8);
          }
        }
#pragma unroll
        for (int n = 0; n < 4; ++n) {
          const size_t ci = ((size_t)node * 4 + ks) * 8 + h * 4 + n;
          s16x8 wf = *(const s16x8*)(Wp + (ci << 9) + lane * 8);
#pragma unroll
          for (int p = 0; p < NDEG; ++p)
            acc[n] = __builtin_amdgcn_mfma_f32_16x16x32_bf16(af[p], wf, acc[n], 0, 0, 0);
        }
      }

      // epilogue
#pragma unroll
      for (int n = 0; n < 4; ++n) {
        const int col = (h * 4 + n) * 16 + lr;
        const float bv = bias[(size_t)node * DIM + col];
        if (dv >= 0) {
          char* db = lds + (size_t)dv * TILE_B;
#pragma unroll
          for (int j = 0; j < 4; ++j) {
            const int row = lg * 4 + j;
            float v = fmaxf(acc[n][j] + bv, 0.f);
            *(uint16_t*)(db + ((row * 256 + col * 2) ^ ((row & 7) << 4))) = (uint16_t)f2bf(v);
          }
        } else if (dv == -1) {
          uint16_t* gb = outs + (size_t)node * NODE_ELEMS + (size_t)row0 * DIM + col;
#pragma unroll
          for (int j = 0; j < 4; ++j) {
            const int row = lg * 4 + j;
            float v = fmaxf(acc[n][j] + bv, 0.f);
            gb[(size_t)row * DIM] = (uint16_t)f2bf(v);
          }
        } else {  // -2: accumulate into f32 mean buffer
#pragma unroll
          for (int j = 0; j < 4; ++j) {
            const int row = lg * 4 + j;
            float v = fmaxf(acc[n][j] + bv, 0.f);
            atomicAdd(mb + row * DIM + col, v);
          }
        }
      }
    }
    __syncthreads();
  }

  // ---- mean store (f32), coalesced ----
  {
    const int r = t >> 7, c = t & 127;
    out[(size_t)(row0 + r) * DIM + c]     = mb[t] * 0.125f;
    out[(size_t)(row0 + 8 + r) * DIM + c] = mb[t + 1024] * 0.125f;
  }
}

// ---------------- host: replicate np.random.default_rng(0) graph ----------------
namespace nprng {
static inline uint32_t hashmix(uint32_t v, uint32_t& hc) {
  v ^= hc; hc *= 0x931e8875u; v *= hc; v ^= v >> 16; return v;
}
static inline uint32_t mixf(uint32_t x, uint32_t y) {
  uint32_t r = x * 0xca01f9ddu - y * 0x4973f715u;
  r ^= r >> 16;
  return r;
}
struct Pcg {
  unsigned __int128 state, inc;
  bool has32; uint32_t saved;
  void step() {
    const unsigned __int128 MUL =
        ((unsigned __int128)2549297995355413924ULL << 64) | 4865540595714422341ULL;
    state = state * MUL + inc;
  }
  void init_seed0() {
    uint32_t pool[4];
    uint32_t hc = 0x43b0d7e5u;
    for (int i = 0; i < 4; ++i) pool[i] = hashmix(0u, hc);
    for (int s = 0; s < 4; ++s)
      for (int d = 0; d < 4; ++d)
        if (s != d) pool[d] = mixf(pool[d], hashmix(pool[s], hc));
    uint32_t st[8];
    uint32_t hb = 0x8b51f9ddu;
    int cyc = 0;
    for (int i = 0; i < 8; ++i) {
      uint32_t dv = pool[cyc]; cyc = (cyc + 1) & 3;
      dv ^= hb; hb *= 0x58f38dedu; dv *= hb; dv ^= dv >> 16;
      st[i] = dv;
    }
    uint64_t v[4];
    for (int i = 0; i < 4; ++i)
      v[i] = (uint64_t)st[2 * i] | ((uint64_t)st[2 * i + 1] << 32);
    unsigned __int128 s128 = ((unsigned __int128)v[0] << 64) | v[1];
    unsigned __int128 i128 = ((unsigned __int128)v[2] << 64) | v[3];
    state = 0; inc = (i128 << 1) | 1;
    step(); state += s128; step();
    has32 = false; saved = 0;
  }
  uint64_t next64() {
    step();
    uint64_t rot = (uint64_t)(state >> 122);
    uint64_t x = (uint64_t)(state >> 64) ^ (uint64_t)state;
    return rot ? ((x >> rot) | (x << (64 - rot))) : x;
  }
  uint32_t next32() {
    if (has32) { has32 = false; return saved; }
    uint64_t v = next64();
    has32 = true; saved = (uint32_t)(v >> 32);
    return (uint32_t)v;
  }
  uint32_t lemire32(uint32_t rng_incl) {
    uint32_t rng_excl = rng_incl + 1u;
    uint64_t m = (uint64_t)next32() * (uint64_t)rng_excl;
    uint32_t leftover = (uint32_t)m;
    if (leftover < rng_excl) {
      uint32_t threshold = (0xFFFFFFFFu - rng_incl) % rng_excl;
      while (leftover < threshold) {
        m = (uint64_t)next32() * (uint64_t)rng_excl;
        leftover = (uint32_t)m;
      }
    }
    return (uint32_t)(m >> 32);
  }
};
}  // namespace nprng

extern "C" void kernel_launch(void* const* d_in, const int* in_sizes, int n_in,
                              void* d_out, int out_size, void* d_ws, size_t ws_size,
                              hipStream_t stream) {
  const float* X    = (const float*)d_in[0];
  const float* W    = (const float*)d_in[1];
  const float* bias = (const float*)d_in[2];
  float* out        = (float*)d_out;

  uint16_t* Wp   = (uint16_t*)d_ws;                                  // 2.13 MB packed W
  uint16_t* outs = (uint16_t*)((char*)d_ws + (size_t)NNODES * DIM * DIM * 2);  // spill space

  // ---- rebuild deterministic graph ----
  nprng::Pcg rng; rng.init_seed0();
  LayerSrcs srcs[NLAYERS];
  int n_prev = 1;
  for (int l = 0; l < NLAYERS; ++l) {
    for (int k = 0; k < KNODES; ++k)
      for (int j = 0; j < NDEG; ++j)
        srcs[l].p[k][j] = (n_prev == 1) ? 0 : (int)rng.lemire32((uint32_t)(n_prev - 1));
    n_prev += KNODES;
  }

  // ---- liveness: alive = contributes to the final mean ----
  bool alive[NNODES];
  for (int i = 0; i < NNODES; ++i) alive[i] = false;
  for (int i = NNODES - KNODES; i < NNODES; ++i) alive[i] = true;
  for (int l = NLAYERS - 1; l >= 0; --l)
    for (int k = 0; k < KNODES; ++k)
      if (alive[1 + l * KNODES + k])
        for (int j = 0; j < NDEG; ++j) alive[srcs[l].p[k][j]] = true;

  int last_use[NNODES];
  for (int i = 0; i < NNODES; ++i) last_use[i] = -1;
  for (int l = 0; l < NLAYERS; ++l)
    for (int k = 0; k < KNODES; ++k)
      if (alive[1 + l * KNODES + k])
        for (int j = 0; j < NDEG; ++j) {
          int s = srcs[l].p[k][j];
          if (l > last_use[s]) last_use[s] = l;
        }

  // ---- slot allocation (greedy, exact graph) ----
  int slot_of[NNODES];
  for (int i = 0; i < NNODES; ++i) slot_of[i] = -1;
  int freeStk[SLOTS], nfree = 0;
  for (int i = SLOTS - 1; i >= 0; --i) freeStk[nfree++] = i;

  Sched sch;
  slot_of[0] = freeStk[--nfree];           // node 0 always alive & first
  sch.root_dst = (int8_t)slot_of[0];

  for (int l = 0; l < NLAYERS; ++l) {
    for (int k = 0; k < KNODES; ++k) {
      const int node = 1 + l * KNODES + k;
      int dv;
      if (!alive[node])            dv = -3;
      else if (l == NLAYERS - 1)   dv = -2;                 // mean-only, LDS f32 accum
      else if (nfree > 0)          dv = slot_of[node] = freeStk[--nfree];
      else                         dv = -1;                 // global spill
      sch.dst[l * KNODES + k] = (int8_t)dv;

      uint64_t w64 = 0;
      for (int j = 0; j < NDEG; ++j) {
        const int src = srcs[l].p[k][j];
        const int enc = ((slot_of[src] + 1) & 0xff) | (src << 8);
        w64 |= (uint64_t)enc << (j * 16);
      }
      sch.pinfo[l * KNODES + k] = w64;
    }
    // free slots whose last use was this layer (reusable from layer l+1 on)
    for (int n = 0; n < NNODES; ++n)
      if (slot_of[n] >= 0 && last_use[n] == l) {
        freeStk[nfree++] = slot_of[n];
        slot_of[n] = -1;
      }
  }

  // ---- launch: 2 kernels total ----
  pack_w<<<dim3(520), dim3(256), 0, stream>>>(W, Wp);
  dag_exec<<<dim3(BATCH / ROWS), dim3(NTHREADS), 0, stream>>>(X, Wp, bias, outs, out, sch);
}